// Round 5
// baseline (304.576 us; speedup 1.0000x reference)
//
#include <hip/hip_runtime.h>

#define N 2048
#define D 128
#define DK 64
#define DG 64
#define SD 8
#define TI 16
#define TJ 128

typedef float f4v __attribute__((ext_vector_type(4)));

// ---------------- kernel 1: projections k = A@Wk+bk, q = A@Wq+bq, appear = A@Wv+bv
__global__ __launch_bounds__(128) void proj_kernel(
    const float* __restrict__ A,
    const float* __restrict__ Wv, const float* __restrict__ bv,
    const float* __restrict__ Wk, const float* __restrict__ bk,
    const float* __restrict__ Wq, const float* __restrict__ bq,
    float* __restrict__ kout, float* __restrict__ qout, float* __restrict__ vout)
{
    __shared__ float arow[D];
    const int i = blockIdx.x;
    const int t = threadIdx.x;
    arow[t] = A[(size_t)i * D + t];
    __syncthreads();
    for (int e = t; e < 2 * DK + SD; e += 128) {
        const float* W; const float* b; int od; int col;
        if (e < DK)            { W = Wk; b = bk; od = DK; col = e; }
        else if (e < 2 * DK)   { W = Wq; b = bq; od = DK; col = e - DK; }
        else                   { W = Wv; b = bv; od = SD; col = e - 2 * DK; }
        float acc = 0.f;
        #pragma unroll 8
        for (int c = 0; c < D; ++c) acc += arow[c] * W[c * od + col];
        acc += b[col];
        if (e < DK)          kout[(size_t)i * DK + col] = acc;
        else if (e < 2 * DK) qout[(size_t)i * DK + col] = acc;
        else                 vout[(size_t)i * SD + col] = acc;
    }
}

// ---------------- kernel 2: gate kernel, shuffle-free LDS-staged consume
// 128 threads = 2 waves. Tile: TI=16 rows x TJ=128 j. Each wave owns j in
// [wv*64, wv*64+64): stages its own 16KB row segment (16 global f4v loads ->
// 16 ds_write_b128, XOR-swizzled), then each THREAD consumes one whole j
// (16 ds_read_b128 + dot with SGPR-resident Wg). No shuffles, no barriers:
// all stage->consume dependencies are same-thread. Double reg batches s0/s1
// keep 2 rows of loads in flight.
__global__ __launch_bounds__(128) void gate_kernel(
    const float* __restrict__ geom,
    const float* __restrict__ Wg, const float* __restrict__ bg,
    const float* __restrict__ kin, const float* __restrict__ qin,
    float* __restrict__ w_nom, float* __restrict__ colpartial)
{
    __shared__ float rbuf[2][TJ * DG];   // 2 x 32 KB
    const int tid  = threadIdx.x;
    const int j0   = blockIdx.x * TJ;
    const int i0   = blockIdx.y * TI;
    const int wv   = tid >> 6;           // wave id 0..1
    const int lane = tid & 63;

    // staging lane assignment: inst t covers jl = wv*64 + t*4 + (lane>>4), chunk m = lane&15
    const int jl_st = wv * 64 + (lane >> 4);
    const int m_st  = lane & 15;
    // consume: thread owns column jl_c = tid (within its own wave's staged segment)
    const int jl_c  = tid;

    const float bgv = bg[0];

    f4v s0[16], s1[16];

#define G_ISSUE(S, row) do {                                                      \
        const float* rb_ = geom + ((size_t)(i0 + (row)) * N + j0) * DG;           \
        _Pragma("unroll")                                                         \
        for (int t_ = 0; t_ < 16; ++t_)                                           \
            S[t_] = *(const f4v*)(rb_ + (size_t)(jl_st + t_ * 4) * DG + m_st * 4);\
    } while (0)

#define G_WRITE(S, bufsel) do {                                                   \
        float* b_ = &rbuf[bufsel][0];                                             \
        _Pragma("unroll")                                                         \
        for (int t_ = 0; t_ < 16; ++t_) {                                         \
            const int jj_ = jl_st + t_ * 4;                                       \
            const int pp_ = m_st ^ (jj_ & 7);                                     \
            *(f4v*)(b_ + jj_ * DG + pp_ * 4) = S[t_];                             \
        }                                                                         \
    } while (0)

#define G_CONSUME(bufsel, row) do {                                               \
        const float* b_ = &rbuf[bufsel][0];                                       \
        float sd_ = 0.f;                                                          \
        _Pragma("unroll")                                                         \
        for (int m_ = 0; m_ < 16; ++m_) {                                         \
            const int pp_ = m_ ^ (jl_c & 7);                                      \
            f4v c_ = *(const f4v*)(b_ + jl_c * DG + pp_ * 4);                     \
            sd_ += c_.x * Wg[4 * m_]     + c_.y * Wg[4 * m_ + 1]                  \
                 + c_.z * Wg[4 * m_ + 2] + c_.w * Wg[4 * m_ + 3];                 \
        }                                                                         \
        sd_ = fmaxf(sd_ + bgv, 0.f);                                              \
        const float val_ = sd_ * expw[row];                                       \
        colacc += val_;                                                           \
        w_nom[(size_t)(i0 + (row)) * N + j0 + jl_c] = val_;                       \
    } while (0)

    // ---- prefetch row 0 (in flight during phase 1)
    G_ISSUE(s0, 0);

    // ---- phase 1: expw[r] = exp((k_{i0+r} . q_{j0+tid})/8), all in registers
    float expw[TI];
    {
        const f4v* qrow = (const f4v*)(qin + (size_t)(j0 + tid) * DK);
        const f4v* krow = (const f4v*)(kin + (size_t)i0 * DK);   // block-uniform
        f4v qv[16];
        #pragma unroll
        for (int m = 0; m < 16; ++m) qv[m] = qrow[m];
        #pragma unroll
        for (int r = 0; r < TI; ++r) {
            float p = 0.f;
            #pragma unroll
            for (int m = 0; m < 16; ++m) {
                const f4v kf = krow[r * 16 + m];                 // uniform -> s_load
                p += kf.x * qv[m].x + kf.y * qv[m].y + kf.z * qv[m].z + kf.w * qv[m].w;
            }
            expw[r] = expf(p * 0.125f);
        }
    }

    // ---- phase 2 prologue: establish invariant
    // top of iter ii (even): buf[0]=row ii, s0=row ii+1 (in flight), s1=row ii+2
    float colacc = 0.f;
    G_WRITE(s0, 0);          // compiler inserts counted vmcnt before ds_writes
    G_ISSUE(s0, 1);
    G_ISSUE(s1, 2);

    #pragma unroll
    for (int ii = 0; ii < TI; ii += 2) {
        // even row
        G_CONSUME(0, ii);
        G_WRITE(s0, 1);                       // row ii+1 -> buf1
        if (ii + 3 < TI) G_ISSUE(s0, ii + 3);
        // odd row
        G_CONSUME(1, ii + 1);
        if (ii + 2 < TI) G_WRITE(s1, 0);      // row ii+2 -> buf0
        if (ii + 4 < TI) G_ISSUE(s1, ii + 4);
    }
#undef G_ISSUE
#undef G_WRITE
#undef G_CONSUME

    // ---- column partial for this i-tile: one value per thread, coalesced
    colpartial[(size_t)blockIdx.y * N + j0 + tid] = colacc;
}

// ---------------- kernel 3: reduce column-partials -> reciprocal of colsum
__global__ __launch_bounds__(256) void colsum_kernel(
    const float* __restrict__ colpartial, float* __restrict__ colrcp)
{
    const int j = blockIdx.x * 256 + threadIdx.x;
    float acc = 0.f;
    #pragma unroll 8
    for (int r = 0; r < N / TI; ++r) acc += colpartial[(size_t)r * N + j];
    colrcp[j] = 1.0f / acc;
}

// ---------------- kernel 4: out[i,s] = sum_j w_nom[i,j]*colrcp[j] * appear[j,s]
__global__ __launch_bounds__(256) void out_kernel(
    const float* __restrict__ w_nom, const float* __restrict__ colrcp,
    const float* __restrict__ appear, float* __restrict__ out)
{
    const int i = blockIdx.x;
    const int t = threadIdx.x;
    float acc[SD];
    #pragma unroll
    for (int s = 0; s < SD; ++s) acc[s] = 0.f;

    #pragma unroll
    for (int jj = 0; jj < N / (256 * 4); ++jj) {
        const int j4 = jj * 256 + t;                 // float4 index
        const f4v wn = ((const f4v*)(w_nom + (size_t)i * N))[j4];
        const f4v rc = ((const f4v*)colrcp)[j4];
        const float w0 = wn.x * rc.x, w1 = wn.y * rc.y, w2 = wn.z * rc.z, w3 = wn.w * rc.w;
        const int j = j4 * 4;
        const f4v* a0 = (const f4v*)(appear + (size_t)j * SD);
        f4v r0 = a0[0], r1 = a0[1];
        f4v r2 = a0[2], r3 = a0[3];
        f4v r4 = a0[4], r5 = a0[5];
        f4v r6 = a0[6], r7 = a0[7];
        acc[0] += w0 * r0.x + w1 * r2.x + w2 * r4.x + w3 * r6.x;
        acc[1] += w0 * r0.y + w1 * r2.y + w2 * r4.y + w3 * r6.y;
        acc[2] += w0 * r0.z + w1 * r2.z + w2 * r4.z + w3 * r6.z;
        acc[3] += w0 * r0.w + w1 * r2.w + w2 * r4.w + w3 * r6.w;
        acc[4] += w0 * r1.x + w1 * r3.x + w2 * r5.x + w3 * r7.x;
        acc[5] += w0 * r1.y + w1 * r3.y + w2 * r5.y + w3 * r7.y;
        acc[6] += w0 * r1.z + w1 * r3.z + w2 * r5.z + w3 * r7.z;
        acc[7] += w0 * r1.w + w1 * r3.w + w2 * r5.w + w3 * r7.w;
    }
    #pragma unroll
    for (int s = 0; s < SD; ++s) {
        #pragma unroll
        for (int off = 32; off >= 1; off >>= 1)
            acc[s] += __shfl_down(acc[s], off);
    }
    __shared__ float red[4][SD];
    const int wave = t >> 6;
    const int lane = t & 63;
    if (lane == 0) {
        #pragma unroll
        for (int s = 0; s < SD; ++s) red[wave][s] = acc[s];
    }
    __syncthreads();
    if (t < SD) out[(size_t)i * SD + t] = red[0][t] + red[1][t] + red[2][t] + red[3][t];
}

extern "C" void kernel_launch(void* const* d_in, const int* in_sizes, int n_in,
                              void* d_out, int out_size, void* d_ws, size_t ws_size,
                              hipStream_t stream) {
    const float* A    = (const float*)d_in[0];
    const float* geom = (const float*)d_in[1];
    const float* Wv   = (const float*)d_in[2];
    const float* bv   = (const float*)d_in[3];
    const float* Wk   = (const float*)d_in[4];
    const float* bk   = (const float*)d_in[5];
    const float* Wq   = (const float*)d_in[6];
    const float* bq   = (const float*)d_in[7];
    const float* Wg   = (const float*)d_in[8];
    const float* bg   = (const float*)d_in[9];
    float* out = (float*)d_out;

    float* ws = (float*)d_ws;
    float* kbuf       = ws;                                 // N*DK
    float* qbuf       = kbuf + (size_t)N * DK;              // N*DK
    float* appear     = qbuf + (size_t)N * DK;              // N*SD
    float* w_nom      = appear + (size_t)N * SD;            // N*N
    float* colpartial = w_nom + (size_t)N * N;              // (N/TI)*N
    float* colrcp     = colpartial + (size_t)(N / TI) * N;  // N

    proj_kernel<<<N, 128, 0, stream>>>(A, Wv, bv, Wk, bk, Wq, bq, kbuf, qbuf, appear);
    gate_kernel<<<dim3(N / TJ, N / TI), 128, 0, stream>>>(geom, Wg, bg, kbuf, qbuf,
                                                          w_nom, colpartial);
    colsum_kernel<<<N / 256, 256, 0, stream>>>(colpartial, colrcp);
    out_kernel<<<N, 256, 0, stream>>>(w_nom, colrcp, appear, out);
}

// Round 6
// 298.359 us; speedup vs baseline: 1.0208x; 1.0208x over previous
//
#include <hip/hip_runtime.h>

#define N 2048
#define D 128
#define DK 64
#define DG 64
#define SD 8
#define TI 32
#define TJ 64

typedef float f4v __attribute__((ext_vector_type(4)));

// ---------------- kernel 1: projections k = A@Wk+bk, q = A@Wq+bq, appear = A@Wv+bv
__global__ __launch_bounds__(128) void proj_kernel(
    const float* __restrict__ A,
    const float* __restrict__ Wv, const float* __restrict__ bv,
    const float* __restrict__ Wk, const float* __restrict__ bk,
    const float* __restrict__ Wq, const float* __restrict__ bq,
    float* __restrict__ kout, float* __restrict__ qout, float* __restrict__ vout)
{
    __shared__ float arow[D];
    const int i = blockIdx.x;
    const int t = threadIdx.x;
    arow[t] = A[(size_t)i * D + t];
    __syncthreads();
    for (int e = t; e < 2 * DK + SD; e += 128) {
        const float* W; const float* b; int od; int col;
        if (e < DK)            { W = Wk; b = bk; od = DK; col = e; }
        else if (e < 2 * DK)   { W = Wq; b = bq; od = DK; col = e - DK; }
        else                   { W = Wv; b = bv; od = SD; col = e - 2 * DK; }
        float acc = 0.f;
        #pragma unroll 8
        for (int c = 0; c < D; ++c) acc += arow[c] * W[c * od + col];
        acc += b[col];
        if (e < DK)          kout[(size_t)i * DK + col] = acc;
        else if (e < 2 * DK) qout[(size_t)i * DK + col] = acc;
        else                 vout[(size_t)i * SD + col] = acc;
    }
}

// ---------------- kernel 2: expA[i,j] = exp((k_i . q_j)/8) into wbuf (fp32)
// 256 threads; thread owns column j = j0+tid; k rows via uniform s_loads.
// 16 rows per block; coalesced 1KB stores per row.
__global__ __launch_bounds__(256) void expa_kernel(
    const float* __restrict__ kin, const float* __restrict__ qin,
    float* __restrict__ expA)
{
    const int tid = threadIdx.x;
    const int j0 = blockIdx.x * 256;
    const int i0 = blockIdx.y * 16;

    const f4v* qrow = (const f4v*)(qin + (size_t)(j0 + tid) * DK);
    f4v qv[16];
    #pragma unroll
    for (int m = 0; m < 16; ++m) qv[m] = qrow[m];

    const f4v* krow = (const f4v*)(kin + (size_t)i0 * DK);   // block-uniform -> s_load
    #pragma unroll
    for (int r = 0; r < 16; ++r) {
        float p = 0.f;
        #pragma unroll
        for (int m = 0; m < 16; ++m) {
            const f4v kf = krow[r * 16 + m];
            p += kf.x * qv[m].x + kf.y * qv[m].y + kf.z * qv[m].z + kf.w * qv[m].w;
        }
        expA[(size_t)(i0 + r) * N + j0 + tid] = expf(p * 0.125f);
    }
}

// ---------------- kernel 3: gate stream kernel (copy-kernel regime)
// 256 threads, no LDS, no barriers. Thread quad owns one j: jl = tid>>2,
// c0 = tid&3 selects chunk set {c0, c0+4, c0+8, c0+12} of the DG=64 row.
// Per row: 4x dwordx4 loads (full 64B lines), 16 FMA, 2 quad shuffles,
// broadcast expA read, in-place w_nom write (same element, same quad).
__global__ __launch_bounds__(256) void gate_kernel(
    const float* __restrict__ geom,
    const float* __restrict__ Wg, const float* __restrict__ bg,
    float* __restrict__ wbuf,          // in: exp(wA); out: w_nom (in-place)
    float* __restrict__ colpartial)
{
    const int tid = threadIdx.x;
    const int j0 = blockIdx.x * TJ;
    const int i0 = blockIdx.y * TI;
    const int jl = tid >> 2;           // 0..63
    const int c0 = tid & 3;
    const int j  = j0 + jl;
    const float bgv = bg[0];

    f4v wgq[4];
    #pragma unroll
    for (int m = 0; m < 4; ++m) wgq[m] = ((const f4v*)Wg)[c0 + 4 * m];

    float colacc = 0.f;

    #pragma unroll 4
    for (int ii = 0; ii < TI; ++ii) {
        const float* rp = geom + ((size_t)(i0 + ii) * N + j) * DG + c0 * 4;
        const f4v g0 = __builtin_nontemporal_load((const f4v*)(rp));
        const f4v g1 = __builtin_nontemporal_load((const f4v*)(rp + 16));
        const f4v g2 = __builtin_nontemporal_load((const f4v*)(rp + 32));
        const f4v g3 = __builtin_nontemporal_load((const f4v*)(rp + 48));
        float s = g0.x * wgq[0].x + g0.y * wgq[0].y + g0.z * wgq[0].z + g0.w * wgq[0].w
                + g1.x * wgq[1].x + g1.y * wgq[1].y + g1.z * wgq[1].z + g1.w * wgq[1].w
                + g2.x * wgq[2].x + g2.y * wgq[2].y + g2.z * wgq[2].z + g2.w * wgq[2].w
                + g3.x * wgq[3].x + g3.y * wgq[3].y + g3.z * wgq[3].z + g3.w * wgq[3].w;
        s += __shfl_xor(s, 1);
        s += __shfl_xor(s, 2);
        s = fmaxf(s + bgv, 0.f);
        float* wp = wbuf + (size_t)(i0 + ii) * N + j;
        const float val = s * (*wp);       // read exp(wA), same element
        colacc += val;
        if (c0 == 0) *wp = val;            // in-place overwrite (single writer)
    }
    if (c0 == 0) colpartial[(size_t)blockIdx.y * N + j] = colacc;
}

// ---------------- kernel 4: reduce column-partials -> reciprocal of colsum
__global__ __launch_bounds__(256) void colsum_kernel(
    const float* __restrict__ colpartial, float* __restrict__ colrcp)
{
    const int j = blockIdx.x * 256 + threadIdx.x;
    float acc = 0.f;
    #pragma unroll 8
    for (int r = 0; r < N / TI; ++r) acc += colpartial[(size_t)r * N + j];
    colrcp[j] = 1.0f / acc;
}

// ---------------- kernel 5: out[i,s] = sum_j w_nom[i,j]*colrcp[j] * appear[j,s]
__global__ __launch_bounds__(256) void out_kernel(
    const float* __restrict__ w_nom, const float* __restrict__ colrcp,
    const float* __restrict__ appear, float* __restrict__ out)
{
    const int i = blockIdx.x;
    const int t = threadIdx.x;
    float acc[SD];
    #pragma unroll
    for (int s = 0; s < SD; ++s) acc[s] = 0.f;

    #pragma unroll
    for (int jj = 0; jj < N / (256 * 4); ++jj) {
        const int j4 = jj * 256 + t;                 // float4 index
        const f4v wn = ((const f4v*)(w_nom + (size_t)i * N))[j4];
        const f4v rc = ((const f4v*)colrcp)[j4];
        const float w0 = wn.x * rc.x, w1 = wn.y * rc.y, w2 = wn.z * rc.z, w3 = wn.w * rc.w;
        const int j = j4 * 4;
        const f4v* a0 = (const f4v*)(appear + (size_t)j * SD);
        f4v r0 = a0[0], r1 = a0[1];
        f4v r2 = a0[2], r3 = a0[3];
        f4v r4 = a0[4], r5 = a0[5];
        f4v r6 = a0[6], r7 = a0[7];
        acc[0] += w0 * r0.x + w1 * r2.x + w2 * r4.x + w3 * r6.x;
        acc[1] += w0 * r0.y + w1 * r2.y + w2 * r4.y + w3 * r6.y;
        acc[2] += w0 * r0.z + w1 * r2.z + w2 * r4.z + w3 * r6.z;
        acc[3] += w0 * r0.w + w1 * r2.w + w2 * r4.w + w3 * r6.w;
        acc[4] += w0 * r1.x + w1 * r3.x + w2 * r5.x + w3 * r7.x;
        acc[5] += w0 * r1.y + w1 * r3.y + w2 * r5.y + w3 * r7.y;
        acc[6] += w0 * r1.z + w1 * r3.z + w2 * r5.z + w3 * r7.z;
        acc[7] += w0 * r1.w + w1 * r3.w + w2 * r5.w + w3 * r7.w;
    }
    #pragma unroll
    for (int s = 0; s < SD; ++s) {
        #pragma unroll
        for (int off = 32; off >= 1; off >>= 1)
            acc[s] += __shfl_down(acc[s], off);
    }
    __shared__ float red[4][SD];
    const int wave = t >> 6;
    const int lane = t & 63;
    if (lane == 0) {
        #pragma unroll
        for (int s = 0; s < SD; ++s) red[wave][s] = acc[s];
    }
    __syncthreads();
    if (t < SD) out[(size_t)i * SD + t] = red[0][t] + red[1][t] + red[2][t] + red[3][t];
}

extern "C" void kernel_launch(void* const* d_in, const int* in_sizes, int n_in,
                              void* d_out, int out_size, void* d_ws, size_t ws_size,
                              hipStream_t stream) {
    const float* A    = (const float*)d_in[0];
    const float* geom = (const float*)d_in[1];
    const float* Wv   = (const float*)d_in[2];
    const float* bv   = (const float*)d_in[3];
    const float* Wk   = (const float*)d_in[4];
    const float* bk   = (const float*)d_in[5];
    const float* Wq   = (const float*)d_in[6];
    const float* bq   = (const float*)d_in[7];
    const float* Wg   = (const float*)d_in[8];
    const float* bg   = (const float*)d_in[9];
    float* out = (float*)d_out;

    float* ws = (float*)d_ws;
    float* kbuf       = ws;                                 // N*DK
    float* qbuf       = kbuf + (size_t)N * DK;              // N*DK
    float* appear     = qbuf + (size_t)N * DK;              // N*SD
    float* wbuf       = appear + (size_t)N * SD;            // N*N (expA -> w_nom)
    float* colpartial = wbuf + (size_t)N * N;               // (N/TI)*N
    float* colrcp     = colpartial + (size_t)(N / TI) * N;  // N

    proj_kernel<<<N, 128, 0, stream>>>(A, Wv, bv, Wk, bk, Wq, bq, kbuf, qbuf, appear);
    expa_kernel<<<dim3(N / 256, N / 16), 256, 0, stream>>>(kbuf, qbuf, wbuf);
    gate_kernel<<<dim3(N / TJ, N / TI), 256, 0, stream>>>(geom, Wg, bg, wbuf, colpartial);
    colsum_kernel<<<N / 256, 256, 0, stream>>>(colpartial, colrcp);
    out_kernel<<<N, 256, 0, stream>>>(wbuf, colrcp, appear, out);
}

// Round 7
// 273.161 us; speedup vs baseline: 1.1150x; 1.0922x over previous
//
#include <hip/hip_runtime.h>

#define N 2048
#define D 128
#define DK 64
#define DG 64
#define SD 8
#define WJ 256   // j-window per gate block pass (4 waves x 64 j)

typedef float f4v __attribute__((ext_vector_type(4)));

// ---------------- kernel 1: projections k = A@Wk+bk, q = A@Wq+bq, appear = A@Wv+bv
__global__ __launch_bounds__(128) void proj_kernel(
    const float* __restrict__ A,
    const float* __restrict__ Wv, const float* __restrict__ bv,
    const float* __restrict__ Wk, const float* __restrict__ bk,
    const float* __restrict__ Wq, const float* __restrict__ bq,
    float* __restrict__ kout, float* __restrict__ qout, float* __restrict__ vout)
{
    __shared__ float arow[D];
    const int i = blockIdx.x;
    const int t = threadIdx.x;
    arow[t] = A[(size_t)i * D + t];
    __syncthreads();
    for (int e = t; e < 2 * DK + SD; e += 128) {
        const float* W; const float* b; int od; int col;
        if (e < DK)            { W = Wk; b = bk; od = DK; col = e; }
        else if (e < 2 * DK)   { W = Wq; b = bq; od = DK; col = e - DK; }
        else                   { W = Wv; b = bv; od = SD; col = e - 2 * DK; }
        float acc = 0.f;
        #pragma unroll 8
        for (int c = 0; c < D; ++c) acc += arow[c] * W[c * od + col];
        acc += b[col];
        if (e < DK)          kout[(size_t)i * DK + col] = acc;
        else if (e < 2 * DK) qout[(size_t)i * DK + col] = acc;
        else                 vout[(size_t)i * SD + col] = acc;
    }
}

// ---------------- kernel 2: expA[i,j] = exp((k_i . q_j)/8) into wbuf (fp32)
__global__ __launch_bounds__(256) void expa_kernel(
    const float* __restrict__ kin, const float* __restrict__ qin,
    float* __restrict__ expA)
{
    const int tid = threadIdx.x;
    const int j0 = blockIdx.x * 256;
    const int i0 = blockIdx.y * 16;

    const f4v* qrow = (const f4v*)(qin + (size_t)(j0 + tid) * DK);
    f4v qv[16];
    #pragma unroll
    for (int m = 0; m < 16; ++m) qv[m] = qrow[m];

    const f4v* krow = (const f4v*)(kin + (size_t)i0 * DK);   // block-uniform -> s_load
    #pragma unroll
    for (int r = 0; r < 16; ++r) {
        float p = 0.f;
        #pragma unroll
        for (int m = 0; m < 16; ++m) {
            const f4v kf = krow[r * 16 + m];
            p += kf.x * qv[m].x + kf.y * qv[m].y + kf.z * qv[m].z + kf.w * qv[m].w;
        }
        expA[(size_t)(i0 + r) * N + j0 + tid] = expf(p * 0.125f);
    }
}

// ---------------- kernel 3: gate stream kernel — one i-row per block,
// fully sequential 512KB geometry stream. 256 threads = 4 waves; per 256-j
// window each wave owns 64 j: 16 x 1KB-contiguous dwordx4 loads (16-lane
// group per j), 4-shuffle group dot-reduce, expA via one coalesced 256B
// read + __shfl broadcast, wave-local LDS gather -> coalesced 256B store
// in place over expA. No barriers (all LDS deps are same-wave).
__global__ __launch_bounds__(256) void gate_kernel(
    const float* __restrict__ geom,
    const float* __restrict__ Wg, const float* __restrict__ bg,
    float* __restrict__ wbuf)          // in: exp(wA); out: w_nom (in-place)
{
    __shared__ float gs[4][64];        // 1KB, per-wave gather slice
    const int tid  = threadIdx.x;
    const int i    = blockIdx.x;
    const int wv   = tid >> 6;
    const int lane = tid & 63;
    const int grp  = lane >> 4;        // 0..3
    const int sub  = lane & 15;

    const f4v wg4  = ((const f4v*)Wg)[sub];
    const float bgv = bg[0];

    const float* rowbase = geom + (size_t)i * N * DG;   // 512KB contiguous
    float* wrow = wbuf + (size_t)i * N;

    for (int t = 0; t < N / WJ; ++t) {
        const int jbase = t * WJ + wv * 64;             // this wave's 64-j slice
        const f4v* src = (const f4v*)(rowbase + (size_t)jbase * DG);
        f4v gbb[16];
        #pragma unroll
        for (int q = 0; q < 16; ++q)                    // 16KB contiguous per wave
            gbb[q] = __builtin_nontemporal_load(src + q * 64 + lane);
        const float ew = wrow[jbase + lane];            // coalesced expA slice
        #pragma unroll
        for (int q = 0; q < 16; ++q) {
            float s = gbb[q].x * wg4.x + gbb[q].y * wg4.y
                    + gbb[q].z * wg4.z + gbb[q].w * wg4.w;
            s += __shfl_xor(s, 1);
            s += __shfl_xor(s, 2);
            s += __shfl_xor(s, 4);
            s += __shfl_xor(s, 8);
            s = fmaxf(s + bgv, 0.f);
            const float e = __shfl(ew, q * 4 + grp);    // expA[i, jbase+q*4+grp]
            const float val = s * e;
            if (sub == 0) gs[wv][q * 4 + grp] = val;
        }
        wrow[jbase + lane] = gs[wv][lane];              // coalesced 256B store
    }
}

// ---------------- kernel 4a: column partial sums over w_nom (L3-resident)
__global__ __launch_bounds__(256) void colpart_kernel(
    const float* __restrict__ wbuf, float* __restrict__ colpart)  // [16][N]
{
    const int j  = blockIdx.x * 256 + threadIdx.x;
    const int r0 = blockIdx.y * (N / 16);
    float acc = 0.f;
    #pragma unroll 8
    for (int r = 0; r < N / 16; ++r) acc += wbuf[(size_t)(r0 + r) * N + j];
    colpart[(size_t)blockIdx.y * N + j] = acc;
}

// ---------------- kernel 4b: reduce 16 partials -> reciprocal of colsum
__global__ __launch_bounds__(256) void colrcp_kernel(
    const float* __restrict__ colpart, float* __restrict__ colrcp)
{
    const int j = blockIdx.x * 256 + threadIdx.x;
    float acc = 0.f;
    #pragma unroll
    for (int r = 0; r < 16; ++r) acc += colpart[(size_t)r * N + j];
    colrcp[j] = 1.0f / acc;
}

// ---------------- kernel 5: out[i,s] = sum_j w_nom[i,j]*colrcp[j] * appear[j,s]
__global__ __launch_bounds__(256) void out_kernel(
    const float* __restrict__ w_nom, const float* __restrict__ colrcp,
    const float* __restrict__ appear, float* __restrict__ out)
{
    const int i = blockIdx.x;
    const int t = threadIdx.x;
    float acc[SD];
    #pragma unroll
    for (int s = 0; s < SD; ++s) acc[s] = 0.f;

    #pragma unroll
    for (int jj = 0; jj < N / (256 * 4); ++jj) {
        const int j4 = jj * 256 + t;                 // float4 index
        const f4v wn = ((const f4v*)(w_nom + (size_t)i * N))[j4];
        const f4v rc = ((const f4v*)colrcp)[j4];
        const float w0 = wn.x * rc.x, w1 = wn.y * rc.y, w2 = wn.z * rc.z, w3 = wn.w * rc.w;
        const int j = j4 * 4;
        const f4v* a0 = (const f4v*)(appear + (size_t)j * SD);
        f4v r0 = a0[0], r1 = a0[1];
        f4v r2 = a0[2], r3 = a0[3];
        f4v r4 = a0[4], r5 = a0[5];
        f4v r6 = a0[6], r7 = a0[7];
        acc[0] += w0 * r0.x + w1 * r2.x + w2 * r4.x + w3 * r6.x;
        acc[1] += w0 * r0.y + w1 * r2.y + w2 * r4.y + w3 * r6.y;
        acc[2] += w0 * r0.z + w1 * r2.z + w2 * r4.z + w3 * r6.z;
        acc[3] += w0 * r0.w + w1 * r2.w + w2 * r4.w + w3 * r6.w;
        acc[4] += w0 * r1.x + w1 * r3.x + w2 * r5.x + w3 * r7.x;
        acc[5] += w0 * r1.y + w1 * r3.y + w2 * r5.y + w3 * r7.y;
        acc[6] += w0 * r1.z + w1 * r3.z + w2 * r5.z + w3 * r7.z;
        acc[7] += w0 * r1.w + w1 * r3.w + w2 * r5.w + w3 * r7.w;
    }
    #pragma unroll
    for (int s = 0; s < SD; ++s) {
        #pragma unroll
        for (int off = 32; off >= 1; off >>= 1)
            acc[s] += __shfl_down(acc[s], off);
    }
    __shared__ float red[4][SD];
    const int wave = t >> 6;
    const int lane = t & 63;
    if (lane == 0) {
        #pragma unroll
        for (int s = 0; s < SD; ++s) red[wave][s] = acc[s];
    }
    __syncthreads();
    if (t < SD) out[(size_t)i * SD + t] = red[0][t] + red[1][t] + red[2][t] + red[3][t];
}

extern "C" void kernel_launch(void* const* d_in, const int* in_sizes, int n_in,
                              void* d_out, int out_size, void* d_ws, size_t ws_size,
                              hipStream_t stream) {
    const float* A    = (const float*)d_in[0];
    const float* geom = (const float*)d_in[1];
    const float* Wv   = (const float*)d_in[2];
    const float* bv   = (const float*)d_in[3];
    const float* Wk   = (const float*)d_in[4];
    const float* bk   = (const float*)d_in[5];
    const float* Wq   = (const float*)d_in[6];
    const float* bq   = (const float*)d_in[7];
    const float* Wg   = (const float*)d_in[8];
    const float* bg   = (const float*)d_in[9];
    float* out = (float*)d_out;

    float* ws = (float*)d_ws;
    float* kbuf    = ws;                             // N*DK
    float* qbuf    = kbuf + (size_t)N * DK;          // N*DK
    float* appear  = qbuf + (size_t)N * DK;          // N*SD
    float* wbuf    = appear + (size_t)N * SD;        // N*N (expA -> w_nom in place)
    float* colpart = wbuf + (size_t)N * N;           // 16*N
    float* colrcp  = colpart + (size_t)16 * N;       // N

    proj_kernel<<<N, 128, 0, stream>>>(A, Wv, bv, Wk, bk, Wq, bq, kbuf, qbuf, appear);
    expa_kernel<<<dim3(N / 256, N / 16), 256, 0, stream>>>(kbuf, qbuf, wbuf);
    gate_kernel<<<N, 256, 0, stream>>>(geom, Wg, bg, wbuf);
    colpart_kernel<<<dim3(N / 256, 16), 256, 0, stream>>>(wbuf, colpart);
    colrcp_kernel<<<N / 256, 256, 0, stream>>>(colpart, colrcp);
    out_kernel<<<N, 256, 0, stream>>>(wbuf, colrcp, appear, out);
}

// Round 8
// 245.216 us; speedup vs baseline: 1.2421x; 1.1140x over previous
//
#include <hip/hip_runtime.h>

#define N 2048
#define D 128
#define DK 64
#define DG 64
#define SD 8
#define TI 8
#define TJ 256

typedef float f4v __attribute__((ext_vector_type(4)));

// ---------------- kernel 1: projections k = A@Wk+bk, q = A@Wq+bq, appear = A@Wv+bv
__global__ __launch_bounds__(128) void proj_kernel(
    const float* __restrict__ A,
    const float* __restrict__ Wv, const float* __restrict__ bv,
    const float* __restrict__ Wk, const float* __restrict__ bk,
    const float* __restrict__ Wq, const float* __restrict__ bq,
    float* __restrict__ kout, float* __restrict__ qout, float* __restrict__ vout)
{
    __shared__ float arow[D];
    const int i = blockIdx.x;
    const int t = threadIdx.x;
    arow[t] = A[(size_t)i * D + t];
    __syncthreads();
    for (int e = t; e < 2 * DK + SD; e += 128) {
        const float* W; const float* b; int od; int col;
        if (e < DK)            { W = Wk; b = bk; od = DK; col = e; }
        else if (e < 2 * DK)   { W = Wq; b = bq; od = DK; col = e - DK; }
        else                   { W = Wv; b = bv; od = SD; col = e - 2 * DK; }
        float acc = 0.f;
        #pragma unroll 8
        for (int c = 0; c < D; ++c) acc += arow[c] * W[c * od + col];
        acc += b[col];
        if (e < DK)          kout[(size_t)i * DK + col] = acc;
        else if (e < 2 * DK) qout[(size_t)i * DK + col] = acc;
        else                 vout[(size_t)i * SD + col] = acc;
    }
}

// ---------------- kernel 2: gate kernel — R4 structure, phase-2 deconfound:
// half-batch (8-load) double buffering with R4's spread layout, so the wave
// never drains to vmcnt(0) at row boundaries. All else identical to R4.
__global__ __launch_bounds__(256) void gate_kernel(
    const float* __restrict__ geom,
    const float* __restrict__ Wg, const float* __restrict__ bg,
    const float* __restrict__ kin, const float* __restrict__ qin,
    float* __restrict__ w_nom, float* __restrict__ colpartial)
{
    __shared__ float wA[TI * TJ];      // 8 KB: exp(wA), later overwritten by w_nom vals
    const int tid = threadIdx.x;
    const int j0 = blockIdx.x * TJ;
    const int i0 = blockIdx.y * TI;
    const int group = tid >> 4;
    const int sub = tid & 15;

    f4v ga[8], gb[8];

#define H_ISSUE(B, step) do {                                                     \
        const int row_ = (step) >> 1, h_ = (step) & 1;                            \
        const f4v* grow_ = (const f4v*)(geom + ((size_t)(i0 + row_) * N + j0) * DG);\
        _Pragma("unroll")                                                         \
        for (int c_ = 0; c_ < 8; ++c_) {                                          \
            const int cc_ = h_ * 8 + c_;                                          \
            B[c_] = __builtin_nontemporal_load(                                   \
                grow_ + (size_t)(cc_ * 16 + group) * 16 + sub);                   \
        } } while (0)

#define H_CONSUME(B, step) do {                                                   \
        const int row_ = (step) >> 1, h_ = (step) & 1;                            \
        _Pragma("unroll")                                                         \
        for (int c_ = 0; c_ < 8; ++c_) {                                          \
            const int cc_ = h_ * 8 + c_;                                          \
            float s_ = B[c_].x * wg4.x + B[c_].y * wg4.y                          \
                     + B[c_].z * wg4.z + B[c_].w * wg4.w;                         \
            s_ += __shfl_xor(s_, 1);                                              \
            s_ += __shfl_xor(s_, 2);                                              \
            s_ += __shfl_xor(s_, 4);                                              \
            s_ += __shfl_xor(s_, 8);                                              \
            s_ = fmaxf(s_ + bgv, 0.f);                                            \
            const int jl_ = cc_ * 16 + group;                                     \
            const float val_ = s_ * wA[row_ * TJ + jl_];                          \
            colacc[cc_] += val_;                                                  \
            if (sub == 0) wA[row_ * TJ + jl_] = val_;                             \
        } } while (0)

    // ---- prefetch row 0 (both halves, 16 loads in flight during phase 1)
    H_ISSUE(ga, 0);
    H_ISSUE(gb, 1);

    // ---- phase 1: thread owns column jl = tid; k rows via uniform (scalar) loads
    {
        const f4v* qrow = (const f4v*)(qin + (size_t)(j0 + tid) * DK);
        const f4v* krow = (const f4v*)(kin + (size_t)i0 * DK);   // block-uniform
        float acc[TI];
        #pragma unroll
        for (int ch = 0; ch < 2; ++ch) {
            f4v qv[8];
            #pragma unroll
            for (int m = 0; m < 8; ++m) qv[m] = qrow[ch * 8 + m];
            #pragma unroll
            for (int r = 0; r < TI; ++r) {
                float p = ch ? acc[r] : 0.f;
                #pragma unroll
                for (int m = 0; m < 8; ++m) {
                    const f4v kf = krow[r * 16 + ch * 8 + m];    // uniform -> s_load
                    p += kf.x * qv[m].x + kf.y * qv[m].y + kf.z * qv[m].z + kf.w * qv[m].w;
                }
                acc[r] = p;
            }
        }
        #pragma unroll
        for (int r = 0; r < TI; ++r) wA[r * TJ + tid] = expf(acc[r] * 0.125f);
    }
    __syncthreads();

    // ---- phase 2: pipelined half-batch stream (never drains to 0 in flight)
    const f4v wg4 = ((const f4v*)Wg)[sub];
    const float bgv = bg[0];

    float colacc[16];
    #pragma unroll
    for (int cc = 0; cc < 16; ++cc) colacc[cc] = 0.f;

    #pragma unroll
    for (int s = 0; s < 2 * TI; ++s) {
        if ((s & 1) == 0) {
            H_CONSUME(ga, s);
            if (s + 2 < 2 * TI) H_ISSUE(ga, s + 2);
        } else {
            H_CONSUME(gb, s);
            if (s + 2 < 2 * TI) H_ISSUE(gb, s + 2);
        }
    }
#undef H_ISSUE
#undef H_CONSUME

    // ---- column partials (lanes of a 16-group hold identical colacc)
    if (sub == 0) {
        #pragma unroll
        for (int cc = 0; cc < 16; ++cc)
            colpartial[(size_t)blockIdx.y * N + j0 + cc * 16 + group] = colacc[cc];
    }
    __syncthreads();

    // ---- phase 3: coalesced flush of w_nom tile (TI*TJ floats = 512 float4)
    {
        const f4v* src = (const f4v*)wA;
        #pragma unroll
        for (int r = 0; r < TI * TJ / 4; r += 256) {
            const int idx = r + tid;
            const int row = idx >> 6;           // TJ/4 = 64 float4 per row
            const int col = idx & 63;
            ((f4v*)(w_nom + (size_t)(i0 + row) * N + j0))[col] = src[idx];
        }
    }
}

// ---------------- kernel 3: reduce column-partials -> reciprocal of colsum
__global__ __launch_bounds__(256) void colsum_kernel(
    const float* __restrict__ colpartial, float* __restrict__ colrcp)
{
    const int j = blockIdx.x * 256 + threadIdx.x;
    float acc = 0.f;
    #pragma unroll 8
    for (int r = 0; r < N / TI; ++r) acc += colpartial[(size_t)r * N + j];
    colrcp[j] = 1.0f / acc;
}

// ---------------- kernel 4: out[i,s] = sum_j w_nom[i,j]*colrcp[j] * appear[j,s]
__global__ __launch_bounds__(256) void out_kernel(
    const float* __restrict__ w_nom, const float* __restrict__ colrcp,
    const float* __restrict__ appear, float* __restrict__ out)
{
    const int i = blockIdx.x;
    const int t = threadIdx.x;
    float acc[SD];
    #pragma unroll
    for (int s = 0; s < SD; ++s) acc[s] = 0.f;

    #pragma unroll
    for (int jj = 0; jj < N / (256 * 4); ++jj) {
        const int j4 = jj * 256 + t;                 // float4 index
        const f4v wn = ((const f4v*)(w_nom + (size_t)i * N))[j4];
        const f4v rc = ((const f4v*)colrcp)[j4];
        const float w0 = wn.x * rc.x, w1 = wn.y * rc.y, w2 = wn.z * rc.z, w3 = wn.w * rc.w;
        const int j = j4 * 4;
        const f4v* a0 = (const f4v*)(appear + (size_t)j * SD);
        f4v r0 = a0[0], r1 = a0[1];
        f4v r2 = a0[2], r3 = a0[3];
        f4v r4 = a0[4], r5 = a0[5];
        f4v r6 = a0[6], r7 = a0[7];
        acc[0] += w0 * r0.x + w1 * r2.x + w2 * r4.x + w3 * r6.x;
        acc[1] += w0 * r0.y + w1 * r2.y + w2 * r4.y + w3 * r6.y;
        acc[2] += w0 * r0.z + w1 * r2.z + w2 * r4.z + w3 * r6.z;
        acc[3] += w0 * r0.w + w1 * r2.w + w2 * r4.w + w3 * r6.w;
        acc[4] += w0 * r1.x + w1 * r3.x + w2 * r5.x + w3 * r7.x;
        acc[5] += w0 * r1.y + w1 * r3.y + w2 * r5.y + w3 * r7.y;
        acc[6] += w0 * r1.z + w1 * r3.z + w2 * r5.z + w3 * r7.z;
        acc[7] += w0 * r1.w + w1 * r3.w + w2 * r5.w + w3 * r7.w;
    }
    #pragma unroll
    for (int s = 0; s < SD; ++s) {
        #pragma unroll
        for (int off = 32; off >= 1; off >>= 1)
            acc[s] += __shfl_down(acc[s], off);
    }
    __shared__ float red[4][SD];
    const int wave = t >> 6;
    const int lane = t & 63;
    if (lane == 0) {
        #pragma unroll
        for (int s = 0; s < SD; ++s) red[wave][s] = acc[s];
    }
    __syncthreads();
    if (t < SD) out[(size_t)i * SD + t] = red[0][t] + red[1][t] + red[2][t] + red[3][t];
}

extern "C" void kernel_launch(void* const* d_in, const int* in_sizes, int n_in,
                              void* d_out, int out_size, void* d_ws, size_t ws_size,
                              hipStream_t stream) {
    const float* A    = (const float*)d_in[0];
    const float* geom = (const float*)d_in[1];
    const float* Wv   = (const float*)d_in[2];
    const float* bv   = (const float*)d_in[3];
    const float* Wk   = (const float*)d_in[4];
    const float* bk   = (const float*)d_in[5];
    const float* Wq   = (const float*)d_in[6];
    const float* bq   = (const float*)d_in[7];
    const float* Wg   = (const float*)d_in[8];
    const float* bg   = (const float*)d_in[9];
    float* out = (float*)d_out;

    float* ws = (float*)d_ws;
    float* kbuf       = ws;                                 // N*DK
    float* qbuf       = kbuf + (size_t)N * DK;              // N*DK
    float* appear     = qbuf + (size_t)N * DK;              // N*SD
    float* w_nom      = appear + (size_t)N * SD;            // N*N
    float* colpartial = w_nom + (size_t)N * N;              // (N/TI)*N
    float* colrcp     = colpartial + (size_t)(N / TI) * N;  // N

    proj_kernel<<<N, 128, 0, stream>>>(A, Wv, bv, Wk, bk, Wq, bq, kbuf, qbuf, appear);
    gate_kernel<<<dim3(N / TJ, N / TI), 256, 0, stream>>>(geom, Wg, bg, kbuf, qbuf,
                                                          w_nom, colpartial);
    colsum_kernel<<<N / 256, 256, 0, stream>>>(colpartial, colrcp);
    out_kernel<<<N, 256, 0, stream>>>(w_nom, colrcp, appear, out);
}